// Round 2
// baseline (339.876 us; speedup 1.0000x reference)
//
#include <hip/hip_runtime.h>
#include <hip/hip_bf16.h>
#include <cstdint>

#define GAMMA 0.001f

typedef __attribute__((ext_vector_type(8))) short bh8;   // 8 bf16 = 4 VGPRs
typedef __attribute__((ext_vector_type(4))) float f32x4;

// ---------------------------------------------------------------------------
// Kernel 1: support prep — f32 -> bf16 (rows padded 784->800 with zeros),
// s2 = sum(row^2), beta[m,c] = exp(-gamma*s2)*alpha[m,c]
// ---------------------------------------------------------------------------
__global__ __launch_bounds__(256) void prep_support_kernel(
    const float* __restrict__ support, const float* __restrict__ alpha,
    ushort* __restrict__ sup_bf, float* __restrict__ beta) {
  int m = blockIdx.x;
  int tid = threadIdx.x;
  __shared__ float red[256];
  float ss = 0.f;
  if (tid < 196) {
    float4 v = ((const float4*)(support + (size_t)m * 784))[tid];
    ss = v.x * v.x + v.y * v.y + v.z * v.z + v.w * v.w;
    ushort4 p;
    __hip_bfloat16 h;
    h = __float2bfloat16(v.x); p.x = *(ushort*)&h;
    h = __float2bfloat16(v.y); p.y = *(ushort*)&h;
    h = __float2bfloat16(v.z); p.z = *(ushort*)&h;
    h = __float2bfloat16(v.w); p.w = *(ushort*)&h;
    *(ushort4*)(sup_bf + (size_t)m * 800 + tid * 4) = p;
  } else if (tid < 200) {  // pad 784..799
    ushort4 z = {0, 0, 0, 0};
    *(ushort4*)(sup_bf + (size_t)m * 800 + tid * 4) = z;
  }
  red[tid] = ss;
  __syncthreads();
  for (int s = 128; s > 0; s >>= 1) {
    if (tid < s) red[tid] += red[tid + s];
    __syncthreads();
  }
  if (tid == 0) {
    float es = __expf(-GAMMA * red[0]);
    float4 a = ((const float4*)alpha)[m];
    float4 b;
    b.x = es * a.x; b.y = es * a.y; b.z = es * a.z; b.w = es * a.w;
    ((float4*)beta)[m] = b;
  }
}

// ---------------------------------------------------------------------------
// Kernel 2: fused conv1+pool+conv2+pool, 2 images per block.
// Stage1: thread-per-pool-output, float2 LDS reads.
// Stage2: thread ↦ (img,o,y7): full-width float4 row loads (16-lane
// broadcast), streaming row accumulation -> VALU-bound, not LDS-bound.
// Emits bf16 feats (padded to 800) + ef[n] = exp(-gamma*|f|^2). Zeros out.
// ---------------------------------------------------------------------------
__global__ __launch_bounds__(256) void conv_feats_kernel(
    const float* __restrict__ x, const float* __restrict__ w1,
    const float* __restrict__ b1, const float* __restrict__ w2,
    const float* __restrict__ b2, ushort* __restrict__ feats_bf,
    float* __restrict__ ef, float* __restrict__ out) {
  int tid = threadIdx.x;
  int bx = blockIdx.x;  // 2048 blocks, images 2*bx, 2*bx+1
  __shared__ float xp[2][900];        // 30x30 zero-padded input
  __shared__ float a1p[2][2048];      // 8 x 16x16 zero-padded stage1 out
  __shared__ float w1s[72], b1s[8], b2s[16];
  __shared__ float w2t[1152];         // transposed: [(ic*3+dy)*3+dx]*16 + o
  __shared__ alignas(16) ushort fb[2][800];
  __shared__ float red[256];

  for (int t = tid; t < 1800; t += 256) ((float*)xp)[t] = 0.f;
  for (int t = tid; t < 4096; t += 256) ((float*)a1p)[t] = 0.f;
  if (tid < 72) w1s[tid] = w1[tid];
  if (tid < 8) b1s[tid] = b1[tid];
  if (tid < 16) b2s[tid] = b2[tid];
  for (int t = tid; t < 1152; t += 256) {
    int o = t / 72, r = t % 72;  // r = ic*9+dy*3+dx
    w2t[r * 16 + o] = w2[t];
  }
  if (tid < 8) out[bx * 8 + tid] = 0.f;  // zero output (poisoned 0xAA)
  __syncthreads();

  // load both images into padded interiors (float4 never straddles: 28%4==0)
  for (int t = tid; t < 392; t += 256) {
    int img = t >= 196, j = t - img * 196;
    float4 v = ((const float4*)(x + (size_t)(bx * 2 + img) * 784))[j];
    int r = j / 7, c = (j % 7) * 4;
    float* p = &xp[img][(r + 1) * 30 + (c + 1)];
    p[0] = v.x; p[1] = v.y; p[2] = v.z; p[3] = v.w;
  }
  __syncthreads();

  // stage 1: conv1(3x3,SAME)+bias+relu+maxpool2 -> a1p interiors
  for (int idx = tid; idx < 3136; idx += 256) {
    int img = idx >= 1568;
    int rem = idx - img * 1568;
    int c = rem / 196, r2 = rem % 196;
    int ph = r2 / 14, pw = r2 % 14;
    const float* w = &w1s[c * 9];
    const float* xb = &xp[img][(2 * ph) * 30 + (2 * pw)];
    float t[4][4];
#pragma unroll
    for (int a = 0; a < 4; a++) {
      float2 u0 = *(const float2*)(xb + a * 30);
      float2 u1 = *(const float2*)(xb + a * 30 + 2);
      t[a][0] = u0.x; t[a][1] = u0.y; t[a][2] = u1.x; t[a][3] = u1.y;
    }
    float s00 = 0, s01 = 0, s10 = 0, s11 = 0;
#pragma unroll
    for (int dy = 0; dy < 3; dy++)
#pragma unroll
      for (int dx = 0; dx < 3; dx++) {
        float wv = w[dy * 3 + dx];
        s00 += t[dy][dx] * wv;     s01 += t[dy][dx + 1] * wv;
        s10 += t[dy + 1][dx] * wv; s11 += t[dy + 1][dx + 1] * wv;
      }
    float mx = fmaxf(fmaxf(s00, s01), fmaxf(s10, s11));
    a1p[img][c * 256 + (ph + 1) * 16 + (pw + 1)] = fmaxf(mx + b1s[c], 0.f);
  }
  __syncthreads();

  // stage 2: conv2(8ch,3x3,SAME)+bias+relu+maxpool2 -> fb (LDS), fsq
  int img = tid >> 7, r = tid & 127;
  float fsq = 0.f;
  if (r < 112) {
    int o = r & 15, y7 = r >> 4;
    float accT[14], accB[14];
#pragma unroll
    for (int q = 0; q < 14; q++) { accT[q] = 0.f; accB[q] = 0.f; }
    for (int ic = 0; ic < 8; ic++) {
      const float* wb = &w2t[ic * 144 + o];
      float wv[9];
#pragma unroll
      for (int k = 0; k < 9; k++) wv[k] = wb[k * 16];
      const float* ap = &a1p[img][ic * 256 + (2 * y7) * 16];
#pragma unroll
      for (int a = 0; a < 4; a++) {
        float rw[16];
        float4 q0 = *(const float4*)(ap + a * 16 + 0);
        float4 q1 = *(const float4*)(ap + a * 16 + 4);
        float4 q2 = *(const float4*)(ap + a * 16 + 8);
        float4 q3 = *(const float4*)(ap + a * 16 + 12);
        rw[0] = q0.x;  rw[1] = q0.y;  rw[2] = q0.z;  rw[3] = q0.w;
        rw[4] = q1.x;  rw[5] = q1.y;  rw[6] = q1.z;  rw[7] = q1.w;
        rw[8] = q2.x;  rw[9] = q2.y;  rw[10] = q2.z; rw[11] = q2.w;
        rw[12] = q3.x; rw[13] = q3.y; rw[14] = q3.z; rw[15] = q3.w;
        if (a < 3) {  // top conv row (dy = a)
#pragma unroll
          for (int q = 0; q < 14; q++)
            accT[q] += wv[a * 3] * rw[q] + wv[a * 3 + 1] * rw[q + 1] +
                       wv[a * 3 + 2] * rw[q + 2];
        }
        if (a >= 1) {  // bottom conv row (dy = a-1)
#pragma unroll
          for (int q = 0; q < 14; q++)
            accB[q] += wv[(a - 1) * 3] * rw[q] + wv[(a - 1) * 3 + 1] * rw[q + 1] +
                       wv[(a - 1) * 3 + 2] * rw[q + 2];
        }
      }
    }
    float bo = b2s[o];
#pragma unroll
    for (int x7 = 0; x7 < 7; x7++) {
      float mx = fmaxf(fmaxf(accT[2 * x7], accT[2 * x7 + 1]),
                       fmaxf(accB[2 * x7], accB[2 * x7 + 1]));
      float val = fmaxf(mx + bo, 0.f);
      __hip_bfloat16 h = __float2bfloat16(val);
      fb[img][o * 49 + y7 * 7 + x7] = *(ushort*)&h;
      fsq += val * val;
    }
  }
  if (r >= 112 && r < 128) fb[img][672 + r] = 0;  // pad 784..799
  red[tid] = fsq;
  __syncthreads();
  for (int s = 64; s > 0; s >>= 1) {
    if ((tid & 127) < s) red[tid] += red[tid + s];
    __syncthreads();
  }
  if ((tid & 127) == 0) ef[bx * 2 + img] = __expf(-GAMMA * red[tid]);

  // coalesced feats store: 2 x 800 ushorts = 200 x uint4
  for (int t = tid; t < 200; t += 256) {
    int im = t >= 100, j = t - im * 100;
    uint4 v = ((const uint4*)fb[im])[j];
    ((uint4*)(feats_bf + (size_t)(bx * 2 + im) * 800))[j] = v;
  }
}

// ---------------------------------------------------------------------------
// Kernel 3: fused RBF GEMM. 128x128 bf16 MFMA tiles over K=800.
// Grid 1024 = 32 nb x 32 mchunk (256 m-rows, mt-loop of 2 tiles);
// bx%8 == mchunk%8 keeps each B-chunk resident in one XCD's L2.
// LDS k-chunk XOR-swizzle (applied at global source, since global_load_lds
// dest is lane-contiguous) kills the 4 extra conflict cycles per b128 read.
// Epilogue: K=exp(2g*G) folded into out[n,c] += K*beta[m,c]; scaled by ef[n].
// ---------------------------------------------------------------------------
__global__ __launch_bounds__(256) void rbf_gemm_kernel(
    const ushort* __restrict__ feats, const ushort* __restrict__ sup,
    const float* __restrict__ beta, const float* __restrict__ ef,
    float* __restrict__ out) {
  __shared__ ushort As[128 * 32];
  __shared__ ushort Bs[128 * 32];
  int tid = threadIdx.x;
  int wave = tid >> 6, lane = tid & 63;
  int bx = blockIdx.x;
  int mchunk = bx & 31, nb = bx >> 5;
  int n0 = nb * 128;
  int wn = wave >> 1, wm = wave & 1;
  int col = lane & 15, quad = lane >> 4;
  int lr = lane >> 2;
  int swz = ((lane & 3) ^ ((lane >> 3) & 3)) * 8;  // staging k-chunk swizzle
  int csw = (col >> 1) & 3;                        // frag-read swizzle

  f32x4 oa[4][4];  // [i-frag][row-reg] over 4 classes
#pragma unroll
  for (int i = 0; i < 4; i++)
#pragma unroll
    for (int rr = 0; rr < 4; rr++) oa[i][rr] = (f32x4){0, 0, 0, 0};

  for (int mt = 0; mt < 2; ++mt) {
    int m0 = mchunk * 256 + mt * 128;
    f32x4 acc[4][4];
#pragma unroll
    for (int i = 0; i < 4; i++)
#pragma unroll
      for (int j = 0; j < 4; j++) acc[i][j] = (f32x4){0, 0, 0, 0};

    for (int kk = 0; kk < 25; ++kk) {
      int k0 = kk * 32;
#pragma unroll
      for (int i = 0; i < 2; i++) {
        int row = wave * 32 + i * 16 + lr;
        const ushort* ga = feats + (size_t)(n0 + row) * 800 + k0 + swz;
        ushort* la = (ushort*)As + row * 32 + (lane & 3) * 8;
        __builtin_amdgcn_global_load_lds(
            (const __attribute__((address_space(1))) void*)ga,
            (__attribute__((address_space(3))) void*)la, 16, 0, 0);
        const ushort* gb = sup + (size_t)(m0 + row) * 800 + k0 + swz;
        ushort* lb = (ushort*)Bs + row * 32 + (lane & 3) * 8;
        __builtin_amdgcn_global_load_lds(
            (const __attribute__((address_space(1))) void*)gb,
            (__attribute__((address_space(3))) void*)lb, 16, 0, 0);
      }
      __syncthreads();
      bh8 af[4], bf[4];
#pragma unroll
      for (int i = 0; i < 4; i++)
        af[i] = *(const bh8*)(As + (wn * 64 + i * 16 + col) * 32 +
                              ((quad ^ csw) * 8));
#pragma unroll
      for (int j = 0; j < 4; j++)
        bf[j] = *(const bh8*)(Bs + (wm * 64 + j * 16 + col) * 32 +
                              ((quad ^ csw) * 8));
#pragma unroll
      for (int i = 0; i < 4; i++)
#pragma unroll
        for (int j = 0; j < 4; j++)
          acc[i][j] = __builtin_amdgcn_mfma_f32_16x16x32_bf16(af[i], bf[j],
                                                              acc[i][j], 0, 0, 0);
      __syncthreads();
    }

    // epilogue: C/D layout col=lane&15 (m), row=quad*4+r (n)
#pragma unroll
    for (int j = 0; j < 4; j++) {
      int m = m0 + wm * 64 + j * 16 + col;
      float4 bt = ((const float4*)beta)[m];
#pragma unroll
      for (int i = 0; i < 4; i++)
#pragma unroll
        for (int rr = 0; rr < 4; rr++) {
          float Kv = __expf(2.f * GAMMA * acc[i][j][rr]);
          oa[i][rr].x += Kv * bt.x; oa[i][rr].y += Kv * bt.y;
          oa[i][rr].z += Kv * bt.z; oa[i][rr].w += Kv * bt.w;
        }
    }
  }

  // reduce over the 16 lanes sharing the same n (col dimension)
#pragma unroll
  for (int i = 0; i < 4; i++)
#pragma unroll
    for (int rr = 0; rr < 4; rr++) {
      f32x4 v = oa[i][rr];
#pragma unroll
      for (int s = 1; s < 16; s <<= 1) {
        v.x += __shfl_xor(v.x, s, 16);
        v.y += __shfl_xor(v.y, s, 16);
        v.z += __shfl_xor(v.z, s, 16);
        v.w += __shfl_xor(v.w, s, 16);
      }
      oa[i][rr] = v;
    }
  if (col < 4) {
#pragma unroll
    for (int i = 0; i < 4; i++)
#pragma unroll
      for (int rr = 0; rr < 4; rr++) {
        int n = n0 + wn * 64 + i * 16 + quad * 4 + rr;
        f32x4 v = oa[i][rr];
        float val = (col == 0) ? v.x : (col == 1) ? v.y : (col == 2) ? v.z : v.w;
        atomicAdd(&out[n * 4 + col], ef[n] * val);
      }
  }
}

// ---------------------------------------------------------------------------
extern "C" void kernel_launch(void* const* d_in, const int* in_sizes, int n_in,
                              void* d_out, int out_size, void* d_ws,
                              size_t ws_size, hipStream_t stream) {
  const float* x = (const float*)d_in[0];
  const float* w1 = (const float*)d_in[1];
  const float* b1 = (const float*)d_in[2];
  const float* w2 = (const float*)d_in[3];
  const float* b2 = (const float*)d_in[4];
  const float* support = (const float*)d_in[5];
  const float* alpha = (const float*)d_in[6];
  float* out = (float*)d_out;

  char* ws = (char*)d_ws;
  ushort* sup_bf = (ushort*)ws;                  // 8192*800*2 = 13,107,200 B
  ushort* feats_bf = (ushort*)(ws + 13107200);   // 4096*800*2 =  6,553,600 B
  float* beta = (float*)(ws + 19660800);         // 8192*4*4   =    131,072 B
  float* ef = (float*)(ws + 19791872);           // 4096*4     =     16,384 B

  prep_support_kernel<<<8192, 256, 0, stream>>>(support, alpha, sup_bf, beta);
  conv_feats_kernel<<<2048, 256, 0, stream>>>(x, w1, b1, w2, b2, feats_bf, ef, out);
  rbf_gemm_kernel<<<1024, 256, 0, stream>>>(feats_bf, sup_bf, beta, ef, out);
}

// Round 3
// 228.433 us; speedup vs baseline: 1.4879x; 1.4879x over previous
//
#include <hip/hip_runtime.h>
#include <hip/hip_bf16.h>
#include <cstdint>

#define GAMMA 0.001f
#define KPAD 832  // 784 padded to 26*32

typedef __attribute__((ext_vector_type(8))) short bh8;   // 8 bf16 = 4 VGPRs
typedef __attribute__((ext_vector_type(4))) float f32x4;

// ---------------------------------------------------------------------------
// Kernel 1: support prep — wave per row. f32 -> bf16 (rows padded 784->832),
// s2 = sum(row^2) via shuffle reduce, beta[m,c] = exp(-gamma*s2)*alpha[m,c]
// ---------------------------------------------------------------------------
__global__ __launch_bounds__(256) void prep_support_kernel(
    const float* __restrict__ support, const float* __restrict__ alpha,
    ushort* __restrict__ sup_bf, float* __restrict__ beta) {
  int tid = threadIdx.x, lane = tid & 63, wave = tid >> 6;
  int m = blockIdx.x * 4 + wave;
  const float* row = support + (size_t)m * 784;
  ushort* drow = sup_bf + (size_t)m * KPAD;
  float ss = 0.f;
  for (int j = lane; j < 196; j += 64) {
    float4 v = ((const float4*)row)[j];
    ss += v.x * v.x + v.y * v.y + v.z * v.z + v.w * v.w;
    ushort4 p;
    __hip_bfloat16 h;
    h = __float2bfloat16(v.x); p.x = *(ushort*)&h;
    h = __float2bfloat16(v.y); p.y = *(ushort*)&h;
    h = __float2bfloat16(v.z); p.z = *(ushort*)&h;
    h = __float2bfloat16(v.w); p.w = *(ushort*)&h;
    ((ushort4*)drow)[j] = p;
  }
  if (lane >= 52) {  // slots 196..207 (12 ushort4) zero-pad
    ushort4 z = {0, 0, 0, 0};
    ((ushort4*)drow)[196 + lane - 52] = z;
  }
#pragma unroll
  for (int s = 1; s < 64; s <<= 1) ss += __shfl_xor(ss, s, 64);
  if (lane == 0) {
    float es = __expf(-GAMMA * ss);
    float4 a = ((const float4*)alpha)[m];
    float4 b;
    b.x = es * a.x; b.y = es * a.y; b.z = es * a.z; b.w = es * a.w;
    ((float4*)beta)[m] = b;
  }
}

// ---------------------------------------------------------------------------
// Kernel 2: fused conv1+pool+conv2+pool, 2 images per block (R2 structure).
// Emits bf16 feats (rows padded to 832) + ef[n] = exp(-gamma*|f|^2).
// ---------------------------------------------------------------------------
__global__ __launch_bounds__(256) void conv_feats_kernel(
    const float* __restrict__ x, const float* __restrict__ w1,
    const float* __restrict__ b1, const float* __restrict__ w2,
    const float* __restrict__ b2, ushort* __restrict__ feats_bf,
    float* __restrict__ ef, float* __restrict__ out) {
  int tid = threadIdx.x;
  int bx = blockIdx.x;  // 2048 blocks, images 2*bx, 2*bx+1
  __shared__ float xp[2][900];        // 30x30 zero-padded input
  __shared__ float a1p[2][2048];      // 8 x 16x16 zero-padded stage1 out
  __shared__ float w1s[72], b1s[8], b2s[16];
  __shared__ float w2t[1152];         // transposed: [(ic*3+dy)*3+dx]*16 + o
  __shared__ alignas(16) ushort fb[2][800];
  __shared__ float red[256];

  for (int t = tid; t < 1800; t += 256) ((float*)xp)[t] = 0.f;
  for (int t = tid; t < 4096; t += 256) ((float*)a1p)[t] = 0.f;
  if (tid < 72) w1s[tid] = w1[tid];
  if (tid < 8) b1s[tid] = b1[tid];
  if (tid < 16) b2s[tid] = b2[tid];
  for (int t = tid; t < 1152; t += 256) {
    int o = t / 72, r = t % 72;  // r = ic*9+dy*3+dx
    w2t[r * 16 + o] = w2[t];
  }
  if (tid < 8) out[bx * 8 + tid] = 0.f;  // zero output (poisoned 0xAA)
  __syncthreads();

  // load both images into padded interiors (float4 never straddles: 28%4==0)
  for (int t = tid; t < 392; t += 256) {
    int img = t >= 196, j = t - img * 196;
    float4 v = ((const float4*)(x + (size_t)(bx * 2 + img) * 784))[j];
    int r = j / 7, c = (j % 7) * 4;
    float* p = &xp[img][(r + 1) * 30 + (c + 1)];
    p[0] = v.x; p[1] = v.y; p[2] = v.z; p[3] = v.w;
  }
  __syncthreads();

  // stage 1: conv1(3x3,SAME)+bias+relu+maxpool2 -> a1p interiors
  for (int idx = tid; idx < 3136; idx += 256) {
    int img = idx >= 1568;
    int rem = idx - img * 1568;
    int c = rem / 196, r2 = rem % 196;
    int ph = r2 / 14, pw = r2 % 14;
    const float* w = &w1s[c * 9];
    const float* xb = &xp[img][(2 * ph) * 30 + (2 * pw)];
    float t[4][4];
#pragma unroll
    for (int a = 0; a < 4; a++) {
      float2 u0 = *(const float2*)(xb + a * 30);
      float2 u1 = *(const float2*)(xb + a * 30 + 2);
      t[a][0] = u0.x; t[a][1] = u0.y; t[a][2] = u1.x; t[a][3] = u1.y;
    }
    float s00 = 0, s01 = 0, s10 = 0, s11 = 0;
#pragma unroll
    for (int dy = 0; dy < 3; dy++)
#pragma unroll
      for (int dx = 0; dx < 3; dx++) {
        float wv = w[dy * 3 + dx];
        s00 += t[dy][dx] * wv;     s01 += t[dy][dx + 1] * wv;
        s10 += t[dy + 1][dx] * wv; s11 += t[dy + 1][dx + 1] * wv;
      }
    float mx = fmaxf(fmaxf(s00, s01), fmaxf(s10, s11));
    a1p[img][c * 256 + (ph + 1) * 16 + (pw + 1)] = fmaxf(mx + b1s[c], 0.f);
  }
  __syncthreads();

  // stage 2: conv2(8ch,3x3,SAME)+bias+relu+maxpool2 -> fb (LDS), fsq
  int img = tid >> 7, r = tid & 127;
  float fsq = 0.f;
  if (r < 112) {
    int o = r & 15, y7 = r >> 4;
    float accT[14], accB[14];
#pragma unroll
    for (int q = 0; q < 14; q++) { accT[q] = 0.f; accB[q] = 0.f; }
    for (int ic = 0; ic < 8; ic++) {
      const float* wb = &w2t[ic * 144 + o];
      float wv[9];
#pragma unroll
      for (int k = 0; k < 9; k++) wv[k] = wb[k * 16];
      const float* ap = &a1p[img][ic * 256 + (2 * y7) * 16];
#pragma unroll
      for (int a = 0; a < 4; a++) {
        float rw[16];
        float4 q0 = *(const float4*)(ap + a * 16 + 0);
        float4 q1 = *(const float4*)(ap + a * 16 + 4);
        float4 q2 = *(const float4*)(ap + a * 16 + 8);
        float4 q3 = *(const float4*)(ap + a * 16 + 12);
        rw[0] = q0.x;  rw[1] = q0.y;  rw[2] = q0.z;  rw[3] = q0.w;
        rw[4] = q1.x;  rw[5] = q1.y;  rw[6] = q1.z;  rw[7] = q1.w;
        rw[8] = q2.x;  rw[9] = q2.y;  rw[10] = q2.z; rw[11] = q2.w;
        rw[12] = q3.x; rw[13] = q3.y; rw[14] = q3.z; rw[15] = q3.w;
        if (a < 3) {  // top conv row (dy = a)
#pragma unroll
          for (int q = 0; q < 14; q++)
            accT[q] += wv[a * 3] * rw[q] + wv[a * 3 + 1] * rw[q + 1] +
                       wv[a * 3 + 2] * rw[q + 2];
        }
        if (a >= 1) {  // bottom conv row (dy = a-1)
#pragma unroll
          for (int q = 0; q < 14; q++)
            accB[q] += wv[(a - 1) * 3] * rw[q] + wv[(a - 1) * 3 + 1] * rw[q + 1] +
                       wv[(a - 1) * 3 + 2] * rw[q + 2];
        }
      }
    }
    float bo = b2s[o];
#pragma unroll
    for (int x7 = 0; x7 < 7; x7++) {
      float mx = fmaxf(fmaxf(accT[2 * x7], accT[2 * x7 + 1]),
                       fmaxf(accB[2 * x7], accB[2 * x7 + 1]));
      float val = fmaxf(mx + bo, 0.f);
      __hip_bfloat16 h = __float2bfloat16(val);
      fb[img][o * 49 + y7 * 7 + x7] = *(ushort*)&h;
      fsq += val * val;
    }
  }
  if (r >= 112 && r < 128) fb[img][672 + r] = 0;  // pad 784..799
  red[tid] = fsq;
  __syncthreads();
  for (int s = 64; s > 0; s >>= 1) {
    if ((tid & 127) < s) red[tid] += red[tid + s];
    __syncthreads();
  }
  if ((tid & 127) == 0) ef[bx * 2 + img] = __expf(-GAMMA * red[tid]);

  // coalesced feats store: rows strided to 832 (104 uint4), tail zeroed
  for (int t = tid; t < 208; t += 256) {
    int im = t >= 104, j = t - im * 104;
    uint4 v;
    if (j < 100) v = ((const uint4*)fb[im])[j];
    else { v.x = 0; v.y = 0; v.z = 0; v.w = 0; }
    ((uint4*)(feats_bf + (size_t)(bx * 2 + im) * KPAD))[j] = v;
  }
}

// ---------------------------------------------------------------------------
// Kernel 3: fused RBF GEMM, R1 config (512 blocks = 32nb x 16chunk, mt<4,
// launch_bounds(256,2)) but BK=64 per barrier-pair: two BK=32 sub-tiles
// staged together -> 13 K-iters instead of 25, halving barrier drains.
// Epilogue: K=exp(2g*G) folded into out[n,c] += K*beta[m,c]; scaled by ef[n].
// ---------------------------------------------------------------------------
__global__ __launch_bounds__(256, 2) void rbf_gemm_kernel(
    const ushort* __restrict__ feats, const ushort* __restrict__ sup,
    const float* __restrict__ beta, const float* __restrict__ ef,
    float* __restrict__ out) {
  __shared__ ushort As[2][128 * 32];
  __shared__ ushort Bs[2][128 * 32];
  int tid = threadIdx.x;
  int wave = tid >> 6, lane = tid & 63;
  int bx = blockIdx.x;
  int chunk = bx & 15, nb = bx >> 4;
  int n0 = nb * 128;
  int mbase = chunk * 512;
  int wn = wave >> 1, wm = wave & 1;
  int col = lane & 15, quad = lane >> 4;
  int lr = lane >> 2, lc = (lane & 3) * 8;

  f32x4 oa[4][4];  // [i-frag][row-reg] over 4 classes
#pragma unroll
  for (int i = 0; i < 4; i++)
#pragma unroll
    for (int rr = 0; rr < 4; rr++) oa[i][rr] = (f32x4){0, 0, 0, 0};

  for (int mt = 0; mt < 4; ++mt) {
    int m0 = mbase + mt * 128;
    f32x4 acc[4][4];
#pragma unroll
    for (int i = 0; i < 4; i++)
#pragma unroll
      for (int j = 0; j < 4; j++) acc[i][j] = (f32x4){0, 0, 0, 0};

    for (int kk = 0; kk < 13; ++kk) {
#pragma unroll
      for (int h = 0; h < 2; h++) {
        int k0 = (kk * 2 + h) * 32;
#pragma unroll
        for (int i = 0; i < 2; i++) {
          int row = wave * 32 + i * 16 + lr;
          const ushort* ga = feats + (size_t)(n0 + row) * KPAD + k0 + lc;
          ushort* la = (ushort*)As[h] + row * 32 + lc;
          __builtin_amdgcn_global_load_lds(
              (const __attribute__((address_space(1))) void*)ga,
              (__attribute__((address_space(3))) void*)la, 16, 0, 0);
          const ushort* gb = sup + (size_t)(m0 + row) * KPAD + k0 + lc;
          ushort* lb = (ushort*)Bs[h] + row * 32 + lc;
          __builtin_amdgcn_global_load_lds(
              (const __attribute__((address_space(1))) void*)gb,
              (__attribute__((address_space(3))) void*)lb, 16, 0, 0);
        }
      }
      __syncthreads();
#pragma unroll
      for (int h = 0; h < 2; h++) {
        bh8 af[4], bf[4];
#pragma unroll
        for (int i = 0; i < 4; i++)
          af[i] = *(const bh8*)(As[h] + (wn * 64 + i * 16 + col) * 32 + quad * 8);
#pragma unroll
        for (int j = 0; j < 4; j++)
          bf[j] = *(const bh8*)(Bs[h] + (wm * 64 + j * 16 + col) * 32 + quad * 8);
#pragma unroll
        for (int i = 0; i < 4; i++)
#pragma unroll
          for (int j = 0; j < 4; j++)
            acc[i][j] = __builtin_amdgcn_mfma_f32_16x16x32_bf16(af[i], bf[j],
                                                                acc[i][j], 0, 0, 0);
      }
      __syncthreads();
    }

    // epilogue: C/D layout col=lane&15 (m), row=quad*4+r (n)
#pragma unroll
    for (int j = 0; j < 4; j++) {
      int m = m0 + wm * 64 + j * 16 + col;
      float4 bt = ((const float4*)beta)[m];
#pragma unroll
      for (int i = 0; i < 4; i++)
#pragma unroll
        for (int rr = 0; rr < 4; rr++) {
          float Kv = __expf(2.f * GAMMA * acc[i][j][rr]);
          oa[i][rr].x += Kv * bt.x; oa[i][rr].y += Kv * bt.y;
          oa[i][rr].z += Kv * bt.z; oa[i][rr].w += Kv * bt.w;
        }
    }
  }

  // reduce over the 16 lanes sharing the same n (col dimension)
#pragma unroll
  for (int i = 0; i < 4; i++)
#pragma unroll
    for (int rr = 0; rr < 4; rr++) {
      f32x4 v = oa[i][rr];
#pragma unroll
      for (int s = 1; s < 16; s <<= 1) {
        v.x += __shfl_xor(v.x, s, 16);
        v.y += __shfl_xor(v.y, s, 16);
        v.z += __shfl_xor(v.z, s, 16);
        v.w += __shfl_xor(v.w, s, 16);
      }
      oa[i][rr] = v;
    }
  if (col < 4) {
#pragma unroll
    for (int i = 0; i < 4; i++)
#pragma unroll
      for (int rr = 0; rr < 4; rr++) {
        int n = n0 + wn * 64 + i * 16 + quad * 4 + rr;
        f32x4 v = oa[i][rr];
        float val = (col == 0) ? v.x : (col == 1) ? v.y : (col == 2) ? v.z : v.w;
        atomicAdd(&out[n * 4 + col], ef[n] * val);
      }
  }
}

// ---------------------------------------------------------------------------
extern "C" void kernel_launch(void* const* d_in, const int* in_sizes, int n_in,
                              void* d_out, int out_size, void* d_ws,
                              size_t ws_size, hipStream_t stream) {
  const float* x = (const float*)d_in[0];
  const float* w1 = (const float*)d_in[1];
  const float* b1 = (const float*)d_in[2];
  const float* w2 = (const float*)d_in[3];
  const float* b2 = (const float*)d_in[4];
  const float* support = (const float*)d_in[5];
  const float* alpha = (const float*)d_in[6];
  float* out = (float*)d_out;

  char* ws = (char*)d_ws;
  ushort* sup_bf = (ushort*)ws;                  // 8192*832*2 = 13,631,488 B
  ushort* feats_bf = (ushort*)(ws + 13631488);   // 4096*832*2 =  6,815,744 B
  float* beta = (float*)(ws + 20447232);         // 8192*4*4   =    131,072 B
  float* ef = (float*)(ws + 20578304);           // 4096*4     =     16,384 B

  prep_support_kernel<<<2048, 256, 0, stream>>>(support, alpha, sup_bf, beta);
  conv_feats_kernel<<<2048, 256, 0, stream>>>(x, w1, b1, w2, b2, feats_bf, ef, out);
  rbf_gemm_kernel<<<512, 256, 0, stream>>>(feats_bf, sup_bf, beta, ef, out);
}

// Round 4
// 220.683 us; speedup vs baseline: 1.5401x; 1.0351x over previous
//
#include <hip/hip_runtime.h>
#include <hip/hip_bf16.h>
#include <cstdint>

#define GAMMA 0.001f
#define KPAD 832  // 784 padded to 26*32

typedef __attribute__((ext_vector_type(8))) short bh8;   // 8 bf16 = 4 VGPRs
typedef __attribute__((ext_vector_type(4))) float f32x4;

// ---------------------------------------------------------------------------
// Kernel 1: support prep — wave per row. f32 -> bf16 (rows padded 784->832),
// s2 = sum(row^2) via shuffle reduce, beta[m,c] = exp(-gamma*s2)*alpha[m,c]
// ---------------------------------------------------------------------------
__global__ __launch_bounds__(256) void prep_support_kernel(
    const float* __restrict__ support, const float* __restrict__ alpha,
    ushort* __restrict__ sup_bf, float* __restrict__ beta) {
  int tid = threadIdx.x, lane = tid & 63, wave = tid >> 6;
  int m = blockIdx.x * 4 + wave;
  const float* row = support + (size_t)m * 784;
  ushort* drow = sup_bf + (size_t)m * KPAD;
  float ss = 0.f;
  for (int j = lane; j < 196; j += 64) {
    float4 v = ((const float4*)row)[j];
    ss += v.x * v.x + v.y * v.y + v.z * v.z + v.w * v.w;
    ushort4 p;
    __hip_bfloat16 h;
    h = __float2bfloat16(v.x); p.x = *(ushort*)&h;
    h = __float2bfloat16(v.y); p.y = *(ushort*)&h;
    h = __float2bfloat16(v.z); p.z = *(ushort*)&h;
    h = __float2bfloat16(v.w); p.w = *(ushort*)&h;
    ((ushort4*)drow)[j] = p;
  }
  if (lane >= 52) {  // slots 196..207 (12 ushort4) zero-pad
    ushort4 z = {0, 0, 0, 0};
    ((ushort4*)drow)[196 + lane - 52] = z;
  }
#pragma unroll
  for (int s = 1; s < 64; s <<= 1) ss += __shfl_xor(ss, s, 64);
  if (lane == 0) {
    float es = __expf(-GAMMA * ss);
    float4 a = ((const float4*)alpha)[m];
    float4 b;
    b.x = es * a.x; b.y = es * a.y; b.z = es * a.z; b.w = es * a.w;
    ((float4*)beta)[m] = b;
  }
}

// ---------------------------------------------------------------------------
// Kernel 2: fused conv1+pool+conv2+pool, 2 images per block.
// a1p row stride = 20 floats (80B, 16B-aligned): y7-groups map to bank
// offsets {0,8,16,24} -> stage2 float4 reads conflict-free (was 4-way).
// Emits bf16 feats (rows padded to 832) + ef[n] = exp(-gamma*|f|^2).
// ---------------------------------------------------------------------------
__global__ __launch_bounds__(256) void conv_feats_kernel(
    const float* __restrict__ x, const float* __restrict__ w1,
    const float* __restrict__ b1, const float* __restrict__ w2,
    const float* __restrict__ b2, ushort* __restrict__ feats_bf,
    float* __restrict__ ef, float* __restrict__ out) {
  int tid = threadIdx.x;
  int bx = blockIdx.x;  // 2048 blocks, images 2*bx, 2*bx+1
  __shared__ float xp[2][900];        // 30x30 zero-padded input
  __shared__ float a1p[2][2560];      // 8 planes x 16 rows x stride 20
  __shared__ float w1s[72], b1s[8], b2s[16];
  __shared__ float w2t[1152];         // transposed: [(ic*3+dy)*3+dx]*16 + o
  __shared__ alignas(16) ushort fb[2][800];
  __shared__ float red[256];

  for (int t = tid; t < 1800; t += 256) ((float*)xp)[t] = 0.f;
  for (int t = tid; t < 5120; t += 256) ((float*)a1p)[t] = 0.f;
  if (tid < 72) w1s[tid] = w1[tid];
  if (tid < 8) b1s[tid] = b1[tid];
  if (tid < 16) b2s[tid] = b2[tid];
  for (int t = tid; t < 1152; t += 256) {
    int o = t / 72, r = t % 72;  // r = ic*9+dy*3+dx
    w2t[r * 16 + o] = w2[t];
  }
  if (tid < 8) out[bx * 8 + tid] = 0.f;  // zero output (poisoned 0xAA)
  __syncthreads();

  // load both images into padded interiors (float4 never straddles: 28%4==0)
  for (int t = tid; t < 392; t += 256) {
    int img = t >= 196, j = t - img * 196;
    float4 v = ((const float4*)(x + (size_t)(bx * 2 + img) * 784))[j];
    int r = j / 7, c = (j % 7) * 4;
    float* p = &xp[img][(r + 1) * 30 + (c + 1)];
    p[0] = v.x; p[1] = v.y; p[2] = v.z; p[3] = v.w;
  }
  __syncthreads();

  // stage 1: conv1(3x3,SAME)+bias+relu+maxpool2 -> a1p interiors
  for (int idx = tid; idx < 3136; idx += 256) {
    int img = idx >= 1568;
    int rem = idx - img * 1568;
    int c = rem / 196, r2 = rem % 196;
    int ph = r2 / 14, pw = r2 % 14;
    const float* w = &w1s[c * 9];
    const float* xb = &xp[img][(2 * ph) * 30 + (2 * pw)];
    float t[4][4];
#pragma unroll
    for (int a = 0; a < 4; a++) {
      float2 u0 = *(const float2*)(xb + a * 30);
      float2 u1 = *(const float2*)(xb + a * 30 + 2);
      t[a][0] = u0.x; t[a][1] = u0.y; t[a][2] = u1.x; t[a][3] = u1.y;
    }
    float s00 = 0, s01 = 0, s10 = 0, s11 = 0;
#pragma unroll
    for (int dy = 0; dy < 3; dy++)
#pragma unroll
      for (int dx = 0; dx < 3; dx++) {
        float wv = w[dy * 3 + dx];
        s00 += t[dy][dx] * wv;     s01 += t[dy][dx + 1] * wv;
        s10 += t[dy + 1][dx] * wv; s11 += t[dy + 1][dx + 1] * wv;
      }
    float mx = fmaxf(fmaxf(s00, s01), fmaxf(s10, s11));
    a1p[img][c * 320 + (ph + 1) * 20 + (pw + 1)] = fmaxf(mx + b1s[c], 0.f);
  }
  __syncthreads();

  // stage 2: conv2(8ch,3x3,SAME)+bias+relu+maxpool2 -> fb (LDS), fsq
  int img = tid >> 7, r = tid & 127;
  float fsq = 0.f;
  if (r < 112) {
    int o = r & 15, y7 = r >> 4;
    float accT[14], accB[14];
#pragma unroll
    for (int q = 0; q < 14; q++) { accT[q] = 0.f; accB[q] = 0.f; }
    for (int ic = 0; ic < 8; ic++) {
      const float* wb = &w2t[ic * 144 + o];
      float wv[9];
#pragma unroll
      for (int k = 0; k < 9; k++) wv[k] = wb[k * 16];
      const float* ap = &a1p[img][ic * 320 + (2 * y7) * 20];
#pragma unroll
      for (int a = 0; a < 4; a++) {
        float rw[16];
        float4 q0 = *(const float4*)(ap + a * 20 + 0);
        float4 q1 = *(const float4*)(ap + a * 20 + 4);
        float4 q2 = *(const float4*)(ap + a * 20 + 8);
        float4 q3 = *(const float4*)(ap + a * 20 + 12);
        rw[0] = q0.x;  rw[1] = q0.y;  rw[2] = q0.z;  rw[3] = q0.w;
        rw[4] = q1.x;  rw[5] = q1.y;  rw[6] = q1.z;  rw[7] = q1.w;
        rw[8] = q2.x;  rw[9] = q2.y;  rw[10] = q2.z; rw[11] = q2.w;
        rw[12] = q3.x; rw[13] = q3.y; rw[14] = q3.z; rw[15] = q3.w;
        if (a < 3) {  // top conv row (dy = a)
#pragma unroll
          for (int q = 0; q < 14; q++)
            accT[q] += wv[a * 3] * rw[q] + wv[a * 3 + 1] * rw[q + 1] +
                       wv[a * 3 + 2] * rw[q + 2];
        }
        if (a >= 1) {  // bottom conv row (dy = a-1)
#pragma unroll
          for (int q = 0; q < 14; q++)
            accB[q] += wv[(a - 1) * 3] * rw[q] + wv[(a - 1) * 3 + 1] * rw[q + 1] +
                       wv[(a - 1) * 3 + 2] * rw[q + 2];
        }
      }
    }
    float bo = b2s[o];
#pragma unroll
    for (int x7 = 0; x7 < 7; x7++) {
      float mx = fmaxf(fmaxf(accT[2 * x7], accT[2 * x7 + 1]),
                       fmaxf(accB[2 * x7], accB[2 * x7 + 1]));
      float val = fmaxf(mx + bo, 0.f);
      __hip_bfloat16 h = __float2bfloat16(val);
      fb[img][o * 49 + y7 * 7 + x7] = *(ushort*)&h;
      fsq += val * val;
    }
  }
  if (r >= 112 && r < 128) fb[img][672 + r] = 0;  // pad 784..799
  red[tid] = fsq;
  __syncthreads();
  for (int s = 64; s > 0; s >>= 1) {
    if ((tid & 127) < s) red[tid] += red[tid + s];
    __syncthreads();
  }
  if ((tid & 127) == 0) ef[bx * 2 + img] = __expf(-GAMMA * red[tid]);

  // coalesced feats store: rows strided to 832 (104 uint4), tail zeroed
  for (int t = tid; t < 208; t += 256) {
    int im = t >= 104, j = t - im * 104;
    uint4 v;
    if (j < 100) v = ((const uint4*)fb[im])[j];
    else { v.x = 0; v.y = 0; v.z = 0; v.w = 0; }
    ((uint4*)(feats_bf + (size_t)(bx * 2 + im) * KPAD))[j] = v;
  }
}

// ---------------------------------------------------------------------------
// Kernel 3: fused RBF GEMM, R3 structure (512 blocks = 32nb x 16chunk, mt<4,
// BK=64 per barrier-pair) + global-source XOR swizzle (R2-proven: kills the
// 8-way frag-read bank conflicts; staged chunk at slot s, row r is
// s ^ ((r&15)>>1 & 3), so frag slot = quad ^ ((col>>1)&3), loop-invariant).
// Epilogue: K=exp(2g*G) folded into out[n,c] += K*beta[m,c]; scaled by ef[n].
// ---------------------------------------------------------------------------
__global__ __launch_bounds__(256, 2) void rbf_gemm_kernel(
    const ushort* __restrict__ feats, const ushort* __restrict__ sup,
    const float* __restrict__ beta, const float* __restrict__ ef,
    float* __restrict__ out) {
  __shared__ ushort As[2][128 * 32];
  __shared__ ushort Bs[2][128 * 32];
  int tid = threadIdx.x;
  int wave = tid >> 6, lane = tid & 63;
  int bx = blockIdx.x;
  int chunk = bx & 15, nb = bx >> 4;
  int n0 = nb * 128;
  int mbase = chunk * 512;
  int wn = wave >> 1, wm = wave & 1;
  int col = lane & 15, quad = lane >> 4;
  int lr = lane >> 2;
  int swz = ((lane & 3) ^ ((lane >> 3) & 3)) * 8;  // staging source k-chunk
  int slot = (lane & 3) * 8;                       // fixed LDS dest slot
  int csw = (col >> 1) & 3;                        // frag-read slot swizzle

  f32x4 oa[4][4];  // [i-frag][row-reg] over 4 classes
#pragma unroll
  for (int i = 0; i < 4; i++)
#pragma unroll
    for (int rr = 0; rr < 4; rr++) oa[i][rr] = (f32x4){0, 0, 0, 0};

  for (int mt = 0; mt < 4; ++mt) {
    int m0 = mbase + mt * 128;
    f32x4 acc[4][4];
#pragma unroll
    for (int i = 0; i < 4; i++)
#pragma unroll
      for (int j = 0; j < 4; j++) acc[i][j] = (f32x4){0, 0, 0, 0};

    for (int kk = 0; kk < 13; ++kk) {
#pragma unroll
      for (int h = 0; h < 2; h++) {
        int k0 = (kk * 2 + h) * 32;
#pragma unroll
        for (int i = 0; i < 2; i++) {
          int row = wave * 32 + i * 16 + lr;
          const ushort* ga = feats + (size_t)(n0 + row) * KPAD + k0 + swz;
          ushort* la = (ushort*)As[h] + row * 32 + slot;
          __builtin_amdgcn_global_load_lds(
              (const __attribute__((address_space(1))) void*)ga,
              (__attribute__((address_space(3))) void*)la, 16, 0, 0);
          const ushort* gb = sup + (size_t)(m0 + row) * KPAD + k0 + swz;
          ushort* lb = (ushort*)Bs[h] + row * 32 + slot;
          __builtin_amdgcn_global_load_lds(
              (const __attribute__((address_space(1))) void*)gb,
              (__attribute__((address_space(3))) void*)lb, 16, 0, 0);
        }
      }
      __syncthreads();
#pragma unroll
      for (int h = 0; h < 2; h++) {
        bh8 af[4], bf[4];
#pragma unroll
        for (int i = 0; i < 4; i++)
          af[i] = *(const bh8*)(As[h] + (wn * 64 + i * 16 + col) * 32 +
                                (quad ^ csw) * 8);
#pragma unroll
        for (int j = 0; j < 4; j++)
          bf[j] = *(const bh8*)(Bs[h] + (wm * 64 + j * 16 + col) * 32 +
                                (quad ^ csw) * 8);
#pragma unroll
        for (int i = 0; i < 4; i++)
#pragma unroll
          for (int j = 0; j < 4; j++)
            acc[i][j] = __builtin_amdgcn_mfma_f32_16x16x32_bf16(af[i], bf[j],
                                                                acc[i][j], 0, 0, 0);
      }
      __syncthreads();
    }

    // epilogue: C/D layout col=lane&15 (m), row=quad*4+r (n)
#pragma unroll
    for (int j = 0; j < 4; j++) {
      int m = m0 + wm * 64 + j * 16 + col;
      float4 bt = ((const float4*)beta)[m];
#pragma unroll
      for (int i = 0; i < 4; i++)
#pragma unroll
        for (int rr = 0; rr < 4; rr++) {
          float Kv = __expf(2.f * GAMMA * acc[i][j][rr]);
          oa[i][rr].x += Kv * bt.x; oa[i][rr].y += Kv * bt.y;
          oa[i][rr].z += Kv * bt.z; oa[i][rr].w += Kv * bt.w;
        }
    }
  }

  // reduce over the 16 lanes sharing the same n (col dimension)
#pragma unroll
  for (int i = 0; i < 4; i++)
#pragma unroll
    for (int rr = 0; rr < 4; rr++) {
      f32x4 v = oa[i][rr];
#pragma unroll
      for (int s = 1; s < 16; s <<= 1) {
        v.x += __shfl_xor(v.x, s, 16);
        v.y += __shfl_xor(v.y, s, 16);
        v.z += __shfl_xor(v.z, s, 16);
        v.w += __shfl_xor(v.w, s, 16);
      }
      oa[i][rr] = v;
    }
  if (col < 4) {
#pragma unroll
    for (int i = 0; i < 4; i++)
#pragma unroll
      for (int rr = 0; rr < 4; rr++) {
        int n = n0 + wn * 64 + i * 16 + quad * 4 + rr;
        f32x4 v = oa[i][rr];
        float val = (col == 0) ? v.x : (col == 1) ? v.y : (col == 2) ? v.z : v.w;
        atomicAdd(&out[n * 4 + col], ef[n] * val);
      }
  }
}

// ---------------------------------------------------------------------------
extern "C" void kernel_launch(void* const* d_in, const int* in_sizes, int n_in,
                              void* d_out, int out_size, void* d_ws,
                              size_t ws_size, hipStream_t stream) {
  const float* x = (const float*)d_in[0];
  const float* w1 = (const float*)d_in[1];
  const float* b1 = (const float*)d_in[2];
  const float* w2 = (const float*)d_in[3];
  const float* b2 = (const float*)d_in[4];
  const float* support = (const float*)d_in[5];
  const float* alpha = (const float*)d_in[6];
  float* out = (float*)d_out;

  char* ws = (char*)d_ws;
  ushort* sup_bf = (ushort*)ws;                  // 8192*832*2 = 13,631,488 B
  ushort* feats_bf = (ushort*)(ws + 13631488);   // 4096*832*2 =  6,815,744 B
  float* beta = (float*)(ws + 20447232);         // 8192*4*4   =    131,072 B
  float* ef = (float*)(ws + 20578304);           // 4096*4     =     16,384 B

  prep_support_kernel<<<2048, 256, 0, stream>>>(support, alpha, sup_bf, beta);
  conv_feats_kernel<<<2048, 256, 0, stream>>>(x, w1, b1, w2, b2, feats_bf, ef, out);
  rbf_gemm_kernel<<<512, 256, 0, stream>>>(feats_bf, sup_bf, beta, ef, out);
}